// Round 6
// baseline (269.473 us; speedup 1.0000x reference)
//
#include <hip/hip_runtime.h>
#include <stdint.h>

// LinearBin: out = x @ sign(W)^T + bias   (B=131072, IN=OUT=512, fp32)
// v6: barrier-free, LDS-free streaming MFMA. Each wave: 32 rows x 128 cols,
//     A read global->reg as fp32 (L1/L2 shared within block), cvt_pk->bf16,
//     mfma_f32_32x32x16_bf16, direct coalesced epilogue stores.
//     W pre-binarized to 32x32x16-fragment-major bf16 in d_ws.

#define BATCH   131072
#define IN_F    512
#define OUT_F   512
#define NT      32            // K-steps of 16

using f32x4  = __attribute__((ext_vector_type(4))) float;
using f32x16 = __attribute__((ext_vector_type(16))) float;
using short8 = __attribute__((ext_vector_type(8))) short;
using usv8   = __attribute__((ext_vector_type(8))) unsigned short;
using u32    = uint32_t;

// ---------------- prep: binarize W into 32x32x16-fragment-major bf16 --------
// wf[((kt*16 + nf)*64 + l)*8 + j] = sign(W[nf*32 + (l&31)][kt*16 + (l>>5)*8 + j])
// kt in [0,32), nf in [0,16), l in [0,64), j in [0,8). 512KB total.
__global__ void prep_w(const float* __restrict__ W, unsigned short* __restrict__ wf) {
    int t = blockIdx.x * blockDim.x + threadIdx.x; // 32768 threads
    int l  = t & 63;
    int nf = (t >> 6) & 15;
    int kt = t >> 10;
    int n = nf * 32 + (l & 31);
    int k = kt * 16 + ((l >> 5) << 3);
    const float* src = W + (size_t)n * IN_F + k;
    f32x4 w0 = *(const f32x4*)(src);
    f32x4 w1 = *(const f32x4*)(src + 4);
    usv8 o;
#pragma unroll
    for (int j = 0; j < 4; ++j) {
        o[j]     = (w0[j] >= 0.0f) ? 0x3F80u : 0xBF80u; // +1.0 / -1.0 bf16
        o[j + 4] = (w1[j] >= 0.0f) ? 0x3F80u : 0xBF80u;
    }
    *(usv8*)(wf + (size_t)t * 8) = o;
}

// ---------------- GEMM: no LDS, no barriers ----------------
__global__ __launch_bounds__(256, 3) void gemm_bin(
    const float* __restrict__ X, const unsigned short* __restrict__ WF,
    const float* __restrict__ bias, float* __restrict__ out) {

    const int tid  = threadIdx.x;
    const int lane = tid & 63;
    const int wv   = tid >> 6;                 // 0..3 -> 128-col strip

    const int m0   = blockIdx.x * 32;          // grid = 4096, 32 rows/block
    const int col0 = wv * 128;

    // A addressing: lane holds row m0+(lane&31), k-chunk (lane>>5)*8 (+kt*16)
    const float* xa = X + (size_t)(m0 + (lane & 31)) * IN_F + ((lane >> 5) << 3);
    // B fragment base: nf0 = wv*4; index = ((kt*16 + nf)*64 + lane)*8
    const unsigned short* wb = WF + ((size_t)(wv * 4) * 64 + lane) * 8;

    f32x16 acc[4];
#pragma unroll
    for (int fn = 0; fn < 4; ++fn)
#pragma unroll
        for (int r = 0; r < 16; ++r) acc[fn][r] = 0.0f;

#pragma unroll
    for (int kt = 0; kt < NT; ++kt) {
        f32x4 a0 = *(const f32x4*)(xa + kt * 16);
        f32x4 a1 = *(const f32x4*)(xa + kt * 16 + 4);
        short8 b[4];
#pragma unroll
        for (int fn = 0; fn < 4; ++fn)
            b[fn] = *(const short8*)(wb + kt * 8192 + fn * 512);
        u32 w0, w1, w2, w3;
        asm("v_cvt_pk_bf16_f32 %0, %1, %2" : "=v"(w0) : "v"(a0[0]), "v"(a0[1]));
        asm("v_cvt_pk_bf16_f32 %0, %1, %2" : "=v"(w1) : "v"(a0[2]), "v"(a0[3]));
        asm("v_cvt_pk_bf16_f32 %0, %1, %2" : "=v"(w2) : "v"(a1[0]), "v"(a1[1]));
        asm("v_cvt_pk_bf16_f32 %0, %1, %2" : "=v"(w3) : "v"(a1[2]), "v"(a1[3]));
        union { u32 w[4]; short8 v; } pk;
        pk.w[0] = w0; pk.w[1] = w1; pk.w[2] = w2; pk.w[3] = w3;
        const short8 afr = pk.v;
#pragma unroll
        for (int fn = 0; fn < 4; ++fn)
            acc[fn] = __builtin_amdgcn_mfma_f32_32x32x16_bf16(
                afr, b[fn], acc[fn], 0, 0, 0);
    }

    // ---------- epilogue: C/D col = lane&31, row = (r&3) + 8*(r>>2) + 4*(lane>>5)
    const int c     = lane & 31;
    const int rbase = (lane >> 5) << 2;
    float bv[4];
#pragma unroll
    for (int fn = 0; fn < 4; ++fn) bv[fn] = bias[col0 + fn * 32 + c];
#pragma unroll
    for (int fn = 0; fn < 4; ++fn)
#pragma unroll
        for (int r = 0; r < 16; ++r) {
            const int row = (r & 3) + 8 * (r >> 2) + rbase;
            out[(size_t)(m0 + row) * OUT_F + col0 + fn * 32 + c] = acc[fn][r] + bv[fn];
        }
}

extern "C" void kernel_launch(void* const* d_in, const int* in_sizes, int n_in,
                              void* d_out, int out_size, void* d_ws, size_t ws_size,
                              hipStream_t stream) {
    const float* X    = (const float*)d_in[0];
    const float* W    = (const float*)d_in[1];
    const float* bias = (const float*)d_in[2];
    float* o          = (float*)d_out;
    unsigned short* wf = (unsigned short*)d_ws; // 512KB fragment-major binarized W

    hipLaunchKernelGGL(prep_w, dim3(128), dim3(256), 0, stream, W, wf);
    hipLaunchKernelGGL(gemm_bin, dim3(BATCH / 32), dim3(256), 0, stream,
                       X, wf, bias, o);
}

// Round 8
// 138.658 us; speedup vs baseline: 1.9434x; 1.9434x over previous
//
#include <hip/hip_runtime.h>
#include <stdint.h>

// LinearBin: out = x @ sign(W)^T + bias   (B=131072, IN=OUT=512, fp32)
// v8: v7 with the LDS swizzle-address bug fixed (carry-free XOR form).
//     Whole 64x512 x-strip staged once as bf16 into 64KB LDS (XOR-swizzled),
//     ONE barrier, then 32 barrier-free mfma_32x32x16 K-steps: A via
//     ds_read_b128, B direct-global (1KB coalesced L2 reads), 1-deep register
//     rotation. Bias pre-loaded into acc. 8 waves x (64x64 tile), 2 blocks/CU.

#define BATCH   131072
#define IN_F    512
#define OUT_F   512
#define BM      64
#define NKT     32            // K-steps of 16

using f32x4  = __attribute__((ext_vector_type(4))) float;
using f32x16 = __attribute__((ext_vector_type(16))) float;
using short8 = __attribute__((ext_vector_type(8))) short;
using usv8   = __attribute__((ext_vector_type(8))) unsigned short;
using u32    = uint32_t;

// ---------------- prep: binarize W into 32x32x16-fragment-major bf16 --------
// (verified r6)  wf[((kt*16+nf)*64+l)*8+j] = sign(W[nf*32+(l&31)][kt*16+(l>>5)*8+j])
__global__ void prep_w(const float* __restrict__ W, unsigned short* __restrict__ wf) {
    int t = blockIdx.x * blockDim.x + threadIdx.x; // 32768 threads
    int l  = t & 63;
    int nf = (t >> 6) & 15;
    int kt = t >> 10;
    int n = nf * 32 + (l & 31);
    int k = kt * 16 + ((l >> 5) << 3);
    const float* src = W + (size_t)n * IN_F + k;
    f32x4 w0 = *(const f32x4*)(src);
    f32x4 w1 = *(const f32x4*)(src + 4);
    usv8 o;
#pragma unroll
    for (int j = 0; j < 4; ++j) {
        o[j]     = (w0[j] >= 0.0f) ? 0x3F80u : 0xBF80u; // +1.0 / -1.0 bf16
        o[j + 4] = (w1[j] >= 0.0f) ? 0x3F80u : 0xBF80u;
    }
    *(usv8*)(wf + (size_t)t * 8) = o;
}

// ---------------- GEMM: one barrier, then barrier-free K-loop ----------------
__global__ __launch_bounds__(512, 4) void gemm_bin(
    const float* __restrict__ X, const unsigned short* __restrict__ WF,
    const float* __restrict__ bias, float* __restrict__ out) {

    // 64 rows x 512 bf16, row stride 1KB, 16B slots XOR-swizzled by (row&7).
    __shared__ __align__(16) unsigned short lds[BM * IN_F]; // 64KB

    const int tid  = threadIdx.x;
    const int lane = tid & 63;
    const int wv   = tid >> 6;              // 0..7 -> 64-col strip
    const int m0   = blockIdx.x * BM;       // grid = 2048

    // ---- stage whole x-strip as bf16 (once) ----
    {
        const int r  = tid >> 3;            // 0..63
        const int sg = tid & 7;
        const float* xr = X + (size_t)(m0 + r) * IN_F;
        char* lrow = (char*)lds + r * 1024;
        const int swz = (r & 7) << 4;
#pragma unroll
        for (int p = 0; p < 8; ++p) {
            const int f0 = sg * 8 + p * 64;
            f32x4 a = *(const f32x4*)(xr + f0);
            f32x4 b = *(const f32x4*)(xr + f0 + 4);
            u32 w0, w1, w2, w3;
            asm("v_cvt_pk_bf16_f32 %0, %1, %2" : "=v"(w0) : "v"(a[0]), "v"(a[1]));
            asm("v_cvt_pk_bf16_f32 %0, %1, %2" : "=v"(w1) : "v"(a[2]), "v"(a[3]));
            asm("v_cvt_pk_bf16_f32 %0, %1, %2" : "=v"(w2) : "v"(b[0]), "v"(b[1]));
            asm("v_cvt_pk_bf16_f32 %0, %1, %2" : "=v"(w3) : "v"(b[2]), "v"(b[3]));
            union { u32 w[4]; usv8 v; } pk;
            pk.w[0] = w0; pk.w[1] = w1; pk.w[2] = w2; pk.w[3] = w3;
            *(usv8*)(lrow + ((sg * 16 + p * 128) ^ swz)) = pk.v;
        }
    }

    // ---- bias -> accumulator init (C/D col = lane&31; bias is col-only) ----
    f32x16 acc[2][2];
#pragma unroll
    for (int fn = 0; fn < 2; ++fn) {
        const float bv = bias[wv * 64 + fn * 32 + (lane & 31)];
#pragma unroll
        for (int rg = 0; rg < 2; ++rg)
#pragma unroll
            for (int r = 0; r < 16; ++r) acc[rg][fn][r] = bv;
    }
    __syncthreads();   // the ONLY barrier

    // ---- A/B fragment geometry ----
    // A: lane l -> row rg*32+(l&31), floats kt*16 + (l>>5)*8.
    //    slot byte = (kt*32 + ((l>>5)<<4)) ^ ((row&7)<<4)  -- carry-free XOR,
    //    always < 1024 (v7 bug: XOR/add decomposition carried past bit 4).
    const int arow  = (lane & 31) * 1024;
    const int ak4   = (lane >> 5) << 4;
    const int aswz  = (lane & 7) << 4;
    const char* lptr = (const char*)lds;
    // B: fragment-major; short8 index = (kt*16 + nf)*64 + lane, nf = wv*2+fn
    const short8* wb = (const short8*)(WF) + ((size_t)(wv * 2) * 64 + lane);

#define LDA(dst, kt_)                                                          \
    {                                                                          \
        const int koff_ = ((kt_) * 32 + ak4) ^ aswz;                           \
        _Pragma("unroll")                                                      \
        for (int rg = 0; rg < 2; ++rg)                                         \
            dst[rg] = *(const short8*)(lptr + rg * 32768 + arow + koff_);      \
    }
#define LDB(dst, kt_)                                                          \
    {                                                                          \
        _Pragma("unroll")                                                      \
        for (int fn = 0; fn < 2; ++fn)                                         \
            dst[fn] = wb[(kt_) * 1024 + fn * 64];                              \
    }

    short8 af[2][2], bf[2][2];
    LDA(af[0], 0);
    LDB(bf[0], 0);

#pragma unroll
    for (int kt = 0; kt < NKT; ++kt) {
        const int cur = kt & 1;
        if (kt < NKT - 1) {
            LDB(bf[cur ^ 1], kt + 1);
            LDA(af[cur ^ 1], kt + 1);
        }
#pragma unroll
        for (int rg = 0; rg < 2; ++rg)
#pragma unroll
            for (int fn = 0; fn < 2; ++fn)
                acc[rg][fn] = __builtin_amdgcn_mfma_f32_32x32x16_bf16(
                    af[cur][rg], bf[cur][fn], acc[rg][fn], 0, 0, 0);
    }
#undef LDA
#undef LDB

    // ---- epilogue: direct stores (bias already in acc) ----
    // C/D: col = lane&31, row = (r&3) + 8*(r>>2) + 4*(lane>>5)
    const int c     = lane & 31;
    const int rbase = (lane >> 5) << 2;
#pragma unroll
    for (int rg = 0; rg < 2; ++rg)
#pragma unroll
        for (int fn = 0; fn < 2; ++fn)
#pragma unroll
            for (int r = 0; r < 16; ++r) {
                const int row = rg * 32 + (r & 3) + 8 * (r >> 2) + rbase;
                out[(size_t)(m0 + row) * OUT_F + wv * 64 + fn * 32 + c] =
                    acc[rg][fn][r];
            }
}

extern "C" void kernel_launch(void* const* d_in, const int* in_sizes, int n_in,
                              void* d_out, int out_size, void* d_ws, size_t ws_size,
                              hipStream_t stream) {
    const float* X    = (const float*)d_in[0];
    const float* W    = (const float*)d_in[1];
    const float* bias = (const float*)d_in[2];
    float* o          = (float*)d_out;
    unsigned short* wf = (unsigned short*)d_ws; // 512KB fragment-major binarized W

    hipLaunchKernelGGL(prep_w, dim3(128), dim3(256), 0, stream, W, wf);
    hipLaunchKernelGGL(gemm_bin, dim3(BATCH / BM), dim3(512), 0, stream,
                       X, wf, bias, o);
}